// Round 11
// baseline (32.884 us; speedup 1.0000x reference)
//
#include <hip/hip_runtime.h>

// out = Wv^T * X * Wv (softmax/log-Euclidean machinery collapses: wsum == 1).
// v11: BARRIER-FREE. One matrix per WAVE (512 blocks x 4 independent waves,
// all co-resident: 2 blocks/CU x 256 CU = 512). Each wave streams its X in
// 8 register-double-buffered row panels straight from global, runs stage 1
// (T = X*Wv, 128 MFMA), transposes T through a wave-private 16 KiB LDS slice
// (in-wave ds ordering only -- NO __syncthreads anywhere), then stage 2
// (O = Wv^T*T, 64 MFMA) and direct stores. Wt[4][4] regs, compile-time
// indexed only (rule #20).

typedef unsigned int uint;
typedef unsigned short ushort;
typedef __bf16 bf16x8 __attribute__((ext_vector_type(8)));
typedef float f32x4 __attribute__((ext_vector_type(4)));
typedef uint uint4v __attribute__((ext_vector_type(4)));
typedef uint uint2v __attribute__((ext_vector_type(2)));

#define DIN   128
#define DOUT  64
#define BLOCK 256
#define GRID  512     // 4 waves/block * 512 = 2048 waves = 1 per matrix

#define MFMA(a, b, c) __builtin_amdgcn_mfma_f32_16x16x32_bf16((a), (b), (c), 0, 0, 0)

__device__ __forceinline__ ushort f2bf(float x) {           // RNE, exact
    uint u = __builtin_bit_cast(uint, x);
    u += 0x7FFFu + ((u >> 16) & 1u);
    return (ushort)(u >> 16);
}
__device__ __forceinline__ uint pk2(float a, float b) {     // lo16=a, hi16=b
    return (uint)f2bf(a) | ((uint)f2bf(b) << 16);
}

extern "C" __global__ void __launch_bounds__(BLOCK, 2)
spd_v11_kernel(const float* __restrict__ x, const float* __restrict__ wv,
               float* __restrict__ out)
{
    __shared__ char TtAll[65536];           // 16 KiB per wave, wave-private
    const int t    = threadIdx.x;
    const int lane = t & 63;
    const int w    = t >> 6;
    const int c    = lane & 15;
    const int g    = lane >> 4;
    char* Tt = TtAll + (w << 14);

    const int mat = blockIdx.x * 4 + w;     // block reads 256 KB contiguous
    const float* X = x + (size_t)mat * (DIN * DIN);

    // ---- prologue: issue panel-0 loads (row 16*0+c, k-cols 32kb+8g..+7)
    float4 cur[8], nxt[8];
    {
        const float* p0 = X + (size_t)c * DIN + g * 8;
#pragma unroll
        for (int kb = 0; kb < 4; ++kb) {
            cur[kb * 2]     = *(const float4*)(p0 + kb * 32);
            cur[kb * 2 + 1] = *(const float4*)(p0 + kb * 32 + 4);
        }
    }

    // ---- Wt[idx][kb] = Wv[32kb+8g+j][16idx+c] (regs; compile-time indexed)
    // stage-1 B operand (idx=nt) AND stage-2 A operand (idx=mt2).
    bf16x8 Wt[4][4];
#pragma unroll
    for (int idx = 0; idx < 4; ++idx)
#pragma unroll
        for (int kb = 0; kb < 4; ++kb) {
            float f[8];
#pragma unroll
            for (int j = 0; j < 8; ++j)
                f[j] = wv[(kb * 32 + g * 8 + j) * DOUT + idx * 16 + c];
            uint4v u;
#pragma unroll
            for (int e = 0; e < 4; ++e) u[e] = pk2(f[2 * e], f[2 * e + 1]);
            Wt[idx][kb] = __builtin_bit_cast(bf16x8, u);
        }

    // ---- stage 1 over 8 row panels, register double-buffered
#pragma unroll
    for (int mt = 0; mt < 8; ++mt) {
        if (mt < 7) {
            const float* pr = X + (size_t)(16 * (mt + 1) + c) * DIN + g * 8;
#pragma unroll
            for (int kb = 0; kb < 4; ++kb) {
                nxt[kb * 2]     = *(const float4*)(pr + kb * 32);
                nxt[kb * 2 + 1] = *(const float4*)(pr + kb * 32 + 4);
            }
        }
        bf16x8 Af[4];
#pragma unroll
        for (int kb = 0; kb < 4; ++kb) {
            uint4v u;
            u[0] = pk2(cur[kb * 2].x,     cur[kb * 2].y);
            u[1] = pk2(cur[kb * 2].z,     cur[kb * 2].w);
            u[2] = pk2(cur[kb * 2 + 1].x, cur[kb * 2 + 1].y);
            u[3] = pk2(cur[kb * 2 + 1].z, cur[kb * 2 + 1].w);
            Af[kb] = __builtin_bit_cast(bf16x8, u);
        }
        f32x4 Tacc[4] = {};
#pragma unroll
        for (int nt = 0; nt < 4; ++nt)
#pragma unroll
            for (int kb = 0; kb < 4; ++kb)
                Tacc[nt] = MFMA(Af[kb], Wt[nt][kb], Tacc[nt]);

        // pack + write T panel into Tt (B-fragment order for stage 2):
        // element T[k=16mt+4g+r][n=16nt+c] -> byte
        //   ((mt>>1)*4+nt)*1024 + ((2*(mt&1)+(g>>1))*16 + c)*16 + (g&1)*8 + r*2
#pragma unroll
        for (int nt = 0; nt < 4; ++nt) {
            uint2v p;
            p[0] = pk2(Tacc[nt][0], Tacc[nt][1]);
            p[1] = pk2(Tacc[nt][2], Tacc[nt][3]);
            const int byte = (((mt >> 1) * 4 + nt) << 10)
                           + ((2 * (mt & 1) + (g >> 1)) * 16 + c) * 16
                           + (g & 1) * 8;
            *(uint2v*)(Tt + byte) = p;
        }
        if (mt < 7) {
#pragma unroll
            for (int q = 0; q < 8; ++q) cur[q] = nxt[q];
        }
    }

    // ---- stage 2: O = Wv^T * T (wave-private Tt reads; in-wave lgkmcnt
    // ordering suffices -- same no-barrier pattern as r8's wave-private Tt)
#pragma unroll
    for (int nt2 = 0; nt2 < 4; ++nt2) {
        bf16x8 Bt[4];
#pragma unroll
        for (int kb = 0; kb < 4; ++kb)
            Bt[kb] = *(const bf16x8*)(Tt + ((kb * 4 + nt2) << 10)
                                         + (g * 16 + c) * 16);
        float* ob = out + (size_t)mat * (DOUT * DOUT)
                  + (size_t)(4 * g) * DOUT + nt2 * 16 + c;
#pragma unroll
        for (int mt2 = 0; mt2 < 4; ++mt2) {
            f32x4 acc = {0.f, 0.f, 0.f, 0.f};
#pragma unroll
            for (int kb = 0; kb < 4; ++kb)
                acc = MFMA(Wt[mt2][kb], Bt[kb], acc);
#pragma unroll
            for (int r = 0; r < 4; ++r)
                ob[(size_t)(mt2 * 16 + r) * DOUT] = acc[r];
        }
    }
}

extern "C" void kernel_launch(void* const* d_in, const int* in_sizes, int n_in,
                              void* d_out, int out_size, void* d_ws, size_t ws_size,
                              hipStream_t stream)
{
    const float* x  = (const float*)d_in[0];   // (32,64,128,128) fp32
    const float* wv = (const float*)d_in[3];   // (128,64) fp32
    float* out = (float*)d_out;                // (2048,64,64) fp32

    (void)in_sizes; (void)n_in; (void)d_ws; (void)ws_size; (void)out_size;

    hipLaunchKernelGGL(spd_v11_kernel, dim3(GRID), dim3(BLOCK), 0, stream,
                       x, wv, out);
}

// Round 12
// 27.077 us; speedup vs baseline: 1.2145x; 1.2145x over previous
//
#include <hip/hip_runtime.h>

// out = Wv^T * X * Wv (softmax/log-Euclidean machinery collapses: wsum == 1).
// v12: SYMMETRY-HALVED TRAFFIC, barrier-free, one matrix per wave.
// X = L + D + L^T  =>  out = Y + Y^T,  Y = Wv^T (L + D/2) Wv.
// Only lower-triangle 16x16 tiles of X are read (36/64 = 56% of X traffic);
// the diagonal tile is masked elementwise (k<row: 1, k==row: 0.5, k>row: 0)
// in fp32 before bf16 conversion. Stage 1 (T' = (L+D/2)Wv) runs 80 MFMA/wave
// over register-double-buffered row panels; T' transposes through the
// wave-private 16 KiB LDS slice (v11 mapping, HW-verified); stage 2
// accumulates all of Y in regs (64 MFMA); Y round-trips the same LDS slice
// (XOR-swizzled fp32) to form Y + Y^T; since out is symmetric, stores are
// contiguous float4 runs. NO __syncthreads anywhere. Rule #20 respected:
// all register-array indices are compile-time.

typedef unsigned int uint;
typedef unsigned short ushort;
typedef __bf16 bf16x8 __attribute__((ext_vector_type(8)));
typedef float f32x4 __attribute__((ext_vector_type(4)));
typedef uint uint4v __attribute__((ext_vector_type(4)));
typedef uint uint2v __attribute__((ext_vector_type(2)));

#define DIN   128
#define DOUT  64
#define BLOCK 256
#define GRID  512     // 4 waves/block * 512 = 2048 waves = 1 per matrix

#define MFMA(a, b, c) __builtin_amdgcn_mfma_f32_16x16x32_bf16((a), (b), (c), 0, 0, 0)

__device__ __forceinline__ ushort f2bf(float x) {           // RNE, exact
    uint u = __builtin_bit_cast(uint, x);
    u += 0x7FFFu + ((u >> 16) & 1u);
    return (ushort)(u >> 16);
}
__device__ __forceinline__ uint pk2(float a, float b) {     // lo16=a, hi16=b
    return (uint)f2bf(a) | ((uint)f2bf(b) << 16);
}
__device__ __forceinline__ float wgt(int k, int r) {        // triangle mask
    return k < r ? 1.0f : (k == r ? 0.5f : 0.0f);
}

extern "C" __global__ void __launch_bounds__(BLOCK, 2)
spd_v12_kernel(const float* __restrict__ x, const float* __restrict__ wv,
               float* __restrict__ out)
{
    __shared__ char TtAll[65536];           // 16 KiB per wave, wave-private
    const int t    = threadIdx.x;
    const int lane = t & 63;
    const int w    = t >> 6;
    const int c    = lane & 15;
    const int g    = lane >> 4;
    char* Tt = TtAll + (w << 14);

    const int mat = blockIdx.x * 4 + w;
    const float* X = x + (size_t)mat * (DIN * DIN);

    // ---- prologue: panel-0 loads (kb=0 only; lanes with tile Jl=g>>1 == 0)
    float4 cur[8], nxt[8];
    if ((g >> 1) == 0) {
        const float* p = X + (size_t)c * DIN + 8 * g;
        cur[0] = *(const float4*)p;
        cur[1] = *(const float4*)(p + 4);
    }

    // ---- Wt[idx][kb] = Wv[32kb+8g+j][16idx+c] (regs; compile-time indexed)
    bf16x8 Wt[4][4];
#pragma unroll
    for (int idx = 0; idx < 4; ++idx)
#pragma unroll
        for (int kb = 0; kb < 4; ++kb) {
            float f[8];
#pragma unroll
            for (int j = 0; j < 8; ++j)
                f[j] = wv[(kb * 32 + g * 8 + j) * DOUT + idx * 16 + c];
            uint4v u;
#pragma unroll
            for (int e = 0; e < 4; ++e) u[e] = pk2(f[2 * e], f[2 * e + 1]);
            Wt[idx][kb] = __builtin_bit_cast(bf16x8, u);
        }

    // ---- stage 1: T' = (L + D/2) * Wv over 8 row panels (triangle only)
#pragma unroll
    for (int I = 0; I < 8; ++I) {
        if (I < 7) {                        // prefetch panel I+1 triangle
#pragma unroll
            for (int kb = 0; kb <= (I + 1) / 2; ++kb) {
                const int Jl = 2 * kb + (g >> 1);
                if (Jl <= I + 1) {
                    const float* p = X + (size_t)(16 * (I + 1) + c) * DIN
                                   + 32 * kb + 8 * g;
                    nxt[2 * kb]     = *(const float4*)p;
                    nxt[2 * kb + 1] = *(const float4*)(p + 4);
                }
            }
        }
        // convert (with diagonal-tile masking) to A-fragments
        bf16x8 Af[4];
#pragma unroll
        for (int kb = 0; kb <= I / 2; ++kb) {
            const int Jl = 2 * kb + (g >> 1);
            float4 v0 = cur[2 * kb], v1 = cur[2 * kb + 1];
            if (Jl == I) {                  // diagonal tile: L + D/2 mask
                const int k8 = 32 * kb + 8 * g, row = 16 * I + c;
                v0.x *= wgt(k8 + 0, row); v0.y *= wgt(k8 + 1, row);
                v0.z *= wgt(k8 + 2, row); v0.w *= wgt(k8 + 3, row);
                v1.x *= wgt(k8 + 4, row); v1.y *= wgt(k8 + 5, row);
                v1.z *= wgt(k8 + 6, row); v1.w *= wgt(k8 + 7, row);
            }
            uint4v u;
            u[0] = pk2(v0.x, v0.y); u[1] = pk2(v0.z, v0.w);
            u[2] = pk2(v1.x, v1.y); u[3] = pk2(v1.z, v1.w);
            if (Jl > I) { u[0] = 0u; u[1] = 0u; u[2] = 0u; u[3] = 0u; }
            Af[kb] = __builtin_bit_cast(bf16x8, u);
        }
        f32x4 Tacc[4] = {};
#pragma unroll
        for (int nt = 0; nt < 4; ++nt)
#pragma unroll
            for (int kb = 0; kb <= I / 2; ++kb)
                Tacc[nt] = MFMA(Af[kb], Wt[nt][kb], Tacc[nt]);

        // write T' panel into Tt (v11 B-fragment mapping, HW-verified)
#pragma unroll
        for (int nt = 0; nt < 4; ++nt) {
            uint2v p;
            p[0] = pk2(Tacc[nt][0], Tacc[nt][1]);
            p[1] = pk2(Tacc[nt][2], Tacc[nt][3]);
            const int byte = (((I >> 1) * 4 + nt) << 10)
                           + ((2 * (I & 1) + (g >> 1)) * 16 + c) * 16
                           + (g & 1) * 8;
            *(uint2v*)(Tt + byte) = p;
        }
        if (I < 7) {
#pragma unroll
            for (int q = 0; q < 8; ++q) cur[q] = nxt[q];
        }
    }

    // ---- stage 2: Y = Wv^T * T'  (all 16 tiles resident in regs)
    f32x4 Yacc[4][4] = {};
#pragma unroll
    for (int nt2 = 0; nt2 < 4; ++nt2) {
        bf16x8 Bt[4];
#pragma unroll
        for (int kb = 0; kb < 4; ++kb)
            Bt[kb] = *(const bf16x8*)(Tt + ((kb * 4 + nt2) << 10)
                                         + (g * 16 + c) * 16);
#pragma unroll
        for (int mt2 = 0; mt2 < 4; ++mt2)
#pragma unroll
            for (int kb = 0; kb < 4; ++kb)
                Yacc[mt2][nt2] = MFMA(Wt[mt2][kb], Bt[kb], Yacc[mt2][nt2]);
    }

    // ---- Y -> LDS (fp32, XOR-swizzled float4 chunks), reusing Tt (T' dead)
    // float-index = row*64 + (((col>>2) ^ (row&15))<<2) + (col&3)
#pragma unroll
    for (int mt2 = 0; mt2 < 4; ++mt2)
#pragma unroll
        for (int nt2 = 0; nt2 < 4; ++nt2)
#pragma unroll
            for (int r = 0; r < 4; ++r) {
                const int row = 16 * mt2 + 4 * g + r;
                const int fi  = row * 64
                              + (((4 * nt2 + (c >> 2)) ^ (row & 15)) << 2)
                              + (c & 3);
                *(float*)(Tt + fi * 4) = Yacc[mt2][nt2][r];
            }

    // ---- out = Y + Y^T: lane reads Y[16nt2+c][16mt2+4g..+3] (one float4),
    // adds its own Yacc tile column, stores a contiguous float4 of out
    // (out is symmetric: out[rowr][col_s] = yT[s] + Yacc[mt2][nt2][s]).
    float* ob = out + (size_t)mat * (DOUT * DOUT);
#pragma unroll
    for (int mt2 = 0; mt2 < 4; ++mt2)
#pragma unroll
        for (int nt2 = 0; nt2 < 4; ++nt2) {
            const int rowr = 16 * nt2 + c;
            const int fi   = rowr * 64 + (((4 * mt2 + g) ^ c) << 2);
            f32x4 yT = *(const f32x4*)(Tt + fi * 4);
            f32x4 o4 = yT + Yacc[mt2][nt2];
            *(f32x4*)(ob + (size_t)rowr * DOUT + 16 * mt2 + 4 * g) = o4;
        }
}

extern "C" void kernel_launch(void* const* d_in, const int* in_sizes, int n_in,
                              void* d_out, int out_size, void* d_ws, size_t ws_size,
                              hipStream_t stream)
{
    const float* x  = (const float*)d_in[0];   // (32,64,128,128) fp32
    const float* wv = (const float*)d_in[3];   // (128,64) fp32
    float* out = (float*)d_out;                // (2048,64,64) fp32

    (void)in_sizes; (void)n_in; (void)d_ws; (void)ws_size; (void)out_size;

    hipLaunchKernelGGL(spd_v12_kernel, dim3(GRID), dim3(BLOCK), 0, stream,
                       x, wv, out);
}